// Round 6
// baseline (625.304 us; speedup 1.0000x reference)
//
#include <hip/hip_runtime.h>

#define D 128
#define FILLV 0.5f
#define PAD 16   // counters strided to 64B lines

typedef unsigned short u16;

__device__ __forceinline__ u16 f2bf(float f) {          // RNE fp32 -> bf16
    unsigned u = __float_as_uint(f);
    u += 0x7FFF + ((u >> 16) & 1);
    return (u16)(u >> 16);
}
__device__ __forceinline__ float bf2f(u16 h) {
    return __uint_as_float(((unsigned)h) << 16);
}

// ---------------------------------------------------------------------------
// Convert both feature matrices to bf16 staging copies (RNE).
__global__ void tobf_kernel(const float* __restrict__ x_s, const float* __restrict__ x_t,
                            u16* __restrict__ xb_s, u16* __restrict__ xb_t, long long nd) {
    long long t = (long long)blockIdx.x * blockDim.x + threadIdx.x;
    long long q = nd / 4;                 // float4 chunks per matrix
    const float* x; u16* xb; long long i;
    if (t < q) { x = x_s; xb = xb_s; i = t * 4; }
    else if (t < 2 * q) { x = x_t; xb = xb_t; i = (t - q) * 4; }
    else return;
    float4 v = *(const float4*)(x + i);
    ushort4 o;
    o.x = f2bf(v.x); o.y = f2bf(v.y); o.z = f2bf(v.z); o.w = f2bf(v.w);
    *(ushort4*)(xb + i) = o;
}

// Pass 1: bucket counts only (padded). Bucket j<N keyed by col (s-side pull),
// bucket N+r keyed by row (t-side pull).
__global__ void cnt_kernel(const int* __restrict__ row, const int* __restrict__ col,
                           int* __restrict__ cntp, int E, int N) {
    int e = blockIdx.x * blockDim.x + threadIdx.x;
    if (e >= E) return;
    atomicAdd(&cntp[(size_t)col[e] * PAD], 1);
    atomicAdd(&cntp[((size_t)N + row[e]) * PAD], 1);
}

// --------------------------- 3-phase parallel scan --------------------------
__global__ void scanA_kernel(const int* __restrict__ cntp, int* __restrict__ tsum, int total) {
    __shared__ int sh[256];
    int gid = blockIdx.x * 256 + threadIdx.x;
    sh[threadIdx.x] = (gid < total) ? cntp[(size_t)gid * PAD] : 0;
    __syncthreads();
    for (int off = 128; off > 0; off >>= 1) {
        if (threadIdx.x < off) sh[threadIdx.x] += sh[threadIdx.x + off];
        __syncthreads();
    }
    if (threadIdx.x == 0) tsum[blockIdx.x] = sh[0];
}

__global__ void scanB_kernel(const int* __restrict__ tsum, int* __restrict__ toff, int nt) {
    __shared__ int sh[512];
    int t = threadIdx.x;
    int v = (t < nt) ? tsum[t] : 0;
    sh[t] = v;
    __syncthreads();
    for (int off = 1; off < 512; off <<= 1) {
        int u = 0;
        if (t >= off) u = sh[t - off];
        __syncthreads();
        sh[t] += u;
        __syncthreads();
    }
    if (t < nt) toff[t] = sh[t] - v;
}

__global__ void scanC_kernel(int* __restrict__ cntp, const int* __restrict__ toff,
                             int* __restrict__ start, int total, int grand_total) {
    __shared__ int sh[256];
    int gid = blockIdx.x * 256 + threadIdx.x;
    int v = (gid < total) ? cntp[(size_t)gid * PAD] : 0;
    sh[threadIdx.x] = v;
    __syncthreads();
    for (int off = 1; off < 256; off <<= 1) {
        int u = 0;
        if (threadIdx.x >= off) u = sh[threadIdx.x - off];
        __syncthreads();
        sh[threadIdx.x] += u;
        __syncthreads();
    }
    int run = toff[blockIdx.x] + sh[threadIdx.x] - v;   // exclusive
    if (gid < total) {
        start[gid] = run;
        cntp[(size_t)gid * PAD] = run;   // becomes fill cursor
    }
    if (gid == 0) start[total] = grand_total;
}

// Pass 2: scatter edges; payload = (neighbor idx, RAW weight bits).
__global__ void fill_kernel(const int* __restrict__ row, const int* __restrict__ col,
                            const float* __restrict__ w,
                            int* __restrict__ cntp, int2* __restrict__ edges, int E, int N) {
    int e = blockIdx.x * blockDim.x + threadIdx.x;
    if (e >= E) return;
    int r = row[e], c = col[e];
    int wb = __float_as_int(w[e]);
    int ps = atomicAdd(&cntp[(size_t)c * PAD], 1);
    edges[ps] = make_int2(r, wb);
    int pt = atomicAdd(&cntp[((size_t)N + r) * PAD], 1);
    edges[pt] = make_int2(c, wb);
}

// Degrees from CSR segments, no atomics. Combined dinv[2N] in bucket key space:
//   dinv[j<N]  = 1/(deg_t[j] + FILL)   (bucket j keyed by col -> sum = deg_t)
//   dinv[N+r]  = 1/(deg_s[r] + FILL)   (bucket N+r keyed by row -> sum = deg_s)
__global__ void deginv_kernel(const int* __restrict__ start, const int2* __restrict__ edges,
                              float* __restrict__ dinv, int total) {
    int i = blockIdx.x * blockDim.x + threadIdx.x;
    if (i >= total) return;
    int s0 = start[i], s1 = start[i + 1];
    float s = 0.f;
    for (int k = s0; k < s1; k++) s += __int_as_float(edges[k].y);
    dinv[i] = 1.0f / (s + FILLV);
}

// ---------------------------------------------------------------------------
// Hop-1 pull (both sides). Wave per node; gathers bf16 rows, fp32 accumulate,
// bf16 result. s-side (wid<N) normalizes by dinv_s = dinv[N+.], t-side by dinv[.].
__global__ void pull1_kernel(const int* __restrict__ start, const int2* __restrict__ edges,
                             const float* __restrict__ dinv,
                             const u16* __restrict__ xb_s, const u16* __restrict__ xb_t,
                             const float* __restrict__ x_s, const float* __restrict__ x_t,
                             u16* __restrict__ ab_s, u16* __restrict__ ab_t, int N) {
    int wid0 = (int)(((long long)blockIdx.x * blockDim.x + threadIdx.x) >> 6);
    int wid = __builtin_amdgcn_readfirstlane(wid0);
    int lane = threadIdx.x & 63;
    if (wid >= 2 * N) return;
    const u16* xb; const float* x; u16* ab; int i, o;
    if (wid < N) { i = wid;     o = N; xb = xb_s; x = x_s; ab = ab_s; }
    else         { i = wid - N; o = 0; xb = xb_t; x = x_t; ab = ab_t; }
    int s0 = start[wid], s1 = start[wid + 1];
    float ax = 0.f, ay = 0.f;
    for (int k = s0; k < s1; k++) {
        int2 p = edges[k];
        float wv = __int_as_float(p.y) * dinv[o + p.x];
        ushort2 v = *(const ushort2*)(xb + (size_t)p.x * D + lane * 2);
        ax += wv * bf2f(v.x);
        ay += wv * bf2f(v.y);
    }
    float sw = FILLV * dinv[o + i];
    float2 xv = *(const float2*)(x + (size_t)i * D + lane * 2);   // fp32 self row
    ax += sw * xv.x;
    ay += sw * xv.y;
    ushort2 ov;
    ov.x = f2bf(ax);
    ov.y = f2bf(ay);
    *(ushort2*)(ab + (size_t)i * D + lane * 2) = ov;
}

// Hop-2 pull + fused epilogue:
//   out_half[i] = w0*x[i] + w1*a[i] + w2*(sum wn*a[nb] + FILL*dinv*a[i])
__global__ void pull2_kernel(const int* __restrict__ start, const int2* __restrict__ edges,
                             const float* __restrict__ dinv,
                             const u16* __restrict__ ab_s, const u16* __restrict__ ab_t,
                             const float* __restrict__ x_s, const float* __restrict__ x_t,
                             float* __restrict__ out,
                             const float* __restrict__ w_s, const float* __restrict__ w_t, int N) {
    int wid0 = (int)(((long long)blockIdx.x * blockDim.x + threadIdx.x) >> 6);
    int wid = __builtin_amdgcn_readfirstlane(wid0);
    int lane = threadIdx.x & 63;
    if (wid >= 2 * N) return;
    const u16* ab; const float* x; const float* wv3; int i, o, half;
    if (wid < N) { i = wid;     o = N; ab = ab_s; x = x_s; wv3 = w_s; half = 0; }
    else         { i = wid - N; o = 0; ab = ab_t; x = x_t; wv3 = w_t; half = D; }
    int s0 = start[wid], s1 = start[wid + 1];
    float ax = 0.f, ay = 0.f;
    for (int k = s0; k < s1; k++) {
        int2 p = edges[k];
        float wv = __int_as_float(p.y) * dinv[o + p.x];
        ushort2 v = *(const ushort2*)(ab + (size_t)p.x * D + lane * 2);
        ax += wv * bf2f(v.x);
        ay += wv * bf2f(v.y);
    }
    float sw = FILLV * dinv[o + i];
    ushort2 av2 = *(const ushort2*)(ab + (size_t)i * D + lane * 2);
    float asx = bf2f(av2.x), asy = bf2f(av2.y);
    ax += sw * asx;
    ay += sw * asy;
    float w0 = wv3[0], w1 = wv3[1], w2 = wv3[2];
    float2 xv = *(const float2*)(x + (size_t)i * D + lane * 2);
    float2 ov;
    ov.x = w0 * xv.x + w1 * asx + w2 * ax;
    ov.y = w0 * xv.y + w1 * asy + w2 * ay;
    *(float2*)(out + (size_t)i * 2 * D + half + lane * 2) = ov;
}

// ---------------------------------------------------------------------------
extern "C" void kernel_launch(void* const* d_in, const int* in_sizes, int n_in,
                              void* d_out, int out_size, void* d_ws, size_t ws_size,
                              hipStream_t stream) {
    const float* x_s = (const float*)d_in[0];
    const float* x_t = (const float*)d_in[1];
    const int*   ei  = (const int*)d_in[2];
    const float* ew  = (const float*)d_in[3];
    const float* w_s = (const float*)d_in[4];
    const float* w_t = (const float*)d_in[5];
    const int N = in_sizes[0] / D;
    const int E = in_sizes[3];
    const int* row = ei;
    const int* col = ei + E;

    const int total = 2 * N;
    const int nTiles = (total + 255) / 256;        // <= 512

    // Workspace (4B units unless noted):
    // [dinv 2N][start 2N+2][tsum 512][toff 512][edges 2E int2]
    // [xb_s ND u16][xb_t ND u16][ab_s ND u16][ab_t ND u16]
    // Padded cntp (2N*PAD ints = 6.4MB) aliases ab_s (12.8MB): cntp dies at
    // fill, ab_s is born at pull1 — lifetimes don't overlap.
    float* f      = (float*)d_ws;
    float* dinv   = f;                              // 2N
    int*   start  = (int*)(f + (size_t)total);      // 2N+2
    int*   tsum   = start + (total + 2);
    int*   toff   = tsum + 512;
    int2*  edges  = (int2*)(toff + 512);            // 2E
    u16*   xb_s   = (u16*)(edges + 2 * (size_t)E);
    u16*   xb_t   = xb_s + (size_t)N * D;
    u16*   ab_s   = xb_t + (size_t)N * D;
    u16*   ab_t   = ab_s + (size_t)N * D;
    int*   cntp   = (int*)ab_s;                     // alias, dead before pull1
    float* out    = (float*)d_out;

    hipMemsetAsync(cntp, 0, (size_t)total * PAD * sizeof(int), stream);

    long long nd = (long long)N * D;
    int blkC  = (int)((nd / 2 + 255) / 256);        // 2 matrices, 4 floats/thread
    int blkE  = (E + 255) / 256;
    int blk2N = (total + 255) / 256;
    tobf_kernel<<<blkC, 256, 0, stream>>>(x_s, x_t, xb_s, xb_t, nd);
    cnt_kernel<<<blkE, 256, 0, stream>>>(row, col, cntp, E, N);
    scanA_kernel<<<nTiles, 256, 0, stream>>>(cntp, tsum, total);
    scanB_kernel<<<1, 512, 0, stream>>>(tsum, toff, nTiles);
    scanC_kernel<<<nTiles, 256, 0, stream>>>(cntp, toff, start, total, 2 * E);
    fill_kernel<<<blkE, 256, 0, stream>>>(row, col, ew, cntp, edges, E, N);
    deginv_kernel<<<blk2N, 256, 0, stream>>>(start, edges, dinv, total);

    long long pull_threads = (long long)total * 64;
    int blkP = (int)((pull_threads + 255) / 256);
    pull1_kernel<<<blkP, 256, 0, stream>>>(start, edges, dinv, xb_s, xb_t,
                                           x_s, x_t, ab_s, ab_t, N);
    pull2_kernel<<<blkP, 256, 0, stream>>>(start, edges, dinv, ab_s, ab_t,
                                           x_s, x_t, out, w_s, w_t, N);
}

// Round 7
// 525.822 us; speedup vs baseline: 1.1892x; 1.1892x over previous
//
#include <hip/hip_runtime.h>

#define D 128
#define FILLV 0.5f
#define PAD 16   // counters strided to 64B lines

typedef unsigned short u16;

__device__ __forceinline__ u16 f2bf(float f) {          // RNE fp32 -> bf16
    unsigned u = __float_as_uint(f);
    u += 0x7FFF + ((u >> 16) & 1);
    return (u16)(u >> 16);
}
__device__ __forceinline__ float bf2f(u16 h) {
    return __uint_as_float(((unsigned)h) << 16);
}

// ---------------------------------------------------------------------------
// Convert both feature matrices to bf16 staging copies (RNE).
__global__ void tobf_kernel(const float* __restrict__ x_s, const float* __restrict__ x_t,
                            u16* __restrict__ xb_s, u16* __restrict__ xb_t, long long nd) {
    long long t = (long long)blockIdx.x * blockDim.x + threadIdx.x;
    long long q = nd / 4;
    const float* x; u16* xb; long long i;
    if (t < q) { x = x_s; xb = xb_s; i = t * 4; }
    else if (t < 2 * q) { x = x_t; xb = xb_t; i = (t - q) * 4; }
    else return;
    float4 v = *(const float4*)(x + i);
    ushort4 o;
    o.x = f2bf(v.x); o.y = f2bf(v.y); o.z = f2bf(v.z); o.w = f2bf(v.w);
    *(ushort4*)(xb + i) = o;
}

// Pass 1: counts + weighted degrees fused into the same padded line.
//   line j<N : [cnt (by col), deg_t (by col)]
//   line N+r : [cnt (by row), deg_s (by row)]
__global__ void cnt_deg_kernel(const int* __restrict__ row, const int* __restrict__ col,
                               const float* __restrict__ w,
                               int* __restrict__ cntp, int E, int N) {
    int e = blockIdx.x * blockDim.x + threadIdx.x;
    if (e >= E) return;
    int r = row[e], c = col[e];
    float we = w[e];
    atomicAdd(&cntp[(size_t)c * PAD], 1);
    atomicAdd((float*)&cntp[(size_t)c * PAD + 1], we);
    atomicAdd(&cntp[((size_t)N + r) * PAD], 1);
    atomicAdd((float*)&cntp[((size_t)N + r) * PAD + 1], we);
}

// dinv[i] = 1/(deg[i]+FILL) in bucket-key space: dinv[c]=dinv_t, dinv[N+r]=dinv_s.
__global__ void invert_kernel(const int* __restrict__ cntp, float* __restrict__ dinv, int total) {
    int i = blockIdx.x * blockDim.x + threadIdx.x;
    if (i >= total) return;
    dinv[i] = 1.0f / (__int_as_float(cntp[(size_t)i * PAD + 1]) + FILLV);
}

// --------------------------- 3-phase parallel scan --------------------------
__global__ void scanA_kernel(const int* __restrict__ cntp, int* __restrict__ tsum, int total) {
    __shared__ int sh[256];
    int gid = blockIdx.x * 256 + threadIdx.x;
    sh[threadIdx.x] = (gid < total) ? cntp[(size_t)gid * PAD] : 0;
    __syncthreads();
    for (int off = 128; off > 0; off >>= 1) {
        if (threadIdx.x < off) sh[threadIdx.x] += sh[threadIdx.x + off];
        __syncthreads();
    }
    if (threadIdx.x == 0) tsum[blockIdx.x] = sh[0];
}

__global__ void scanB_kernel(const int* __restrict__ tsum, int* __restrict__ toff, int nt) {
    __shared__ int sh[512];
    int t = threadIdx.x;
    int v = (t < nt) ? tsum[t] : 0;
    sh[t] = v;
    __syncthreads();
    for (int off = 1; off < 512; off <<= 1) {
        int u = 0;
        if (t >= off) u = sh[t - off];
        __syncthreads();
        sh[t] += u;
        __syncthreads();
    }
    if (t < nt) toff[t] = sh[t] - v;
}

__global__ void scanC_kernel(int* __restrict__ cntp, const int* __restrict__ toff,
                             int* __restrict__ start, int total, int grand_total) {
    __shared__ int sh[256];
    int gid = blockIdx.x * 256 + threadIdx.x;
    int v = (gid < total) ? cntp[(size_t)gid * PAD] : 0;
    sh[threadIdx.x] = v;
    __syncthreads();
    for (int off = 1; off < 256; off <<= 1) {
        int u = 0;
        if (threadIdx.x >= off) u = sh[threadIdx.x - off];
        __syncthreads();
        sh[threadIdx.x] += u;
        __syncthreads();
    }
    int run = toff[blockIdx.x] + sh[threadIdx.x] - v;   // exclusive
    if (gid < total) {
        start[gid] = run;
        cntp[(size_t)gid * PAD] = run;   // becomes fill cursor
    }
    if (gid == 0) start[total] = grand_total;
}

// Pass 2: scatter edges with dinv pre-folded: payload = (src, w*dinv[src-key]).
__global__ void fill_kernel(const int* __restrict__ row, const int* __restrict__ col,
                            const float* __restrict__ w, const float* __restrict__ dinv,
                            int* __restrict__ cntp, int2* __restrict__ edges, int E, int N) {
    int e = blockIdx.x * blockDim.x + threadIdx.x;
    if (e >= E) return;
    int r = row[e], c = col[e];
    float we = w[e];
    float wns = we * dinv[N + r];   // s-side: normalize by deg_s (row key)
    float wnt = we * dinv[c];       // t-side: normalize by deg_t (col key)
    int ps = atomicAdd(&cntp[(size_t)c * PAD], 1);
    edges[ps] = make_int2(r, __float_as_int(wns));
    int pt = atomicAdd(&cntp[((size_t)N + r) * PAD], 1);
    edges[pt] = make_int2(c, __float_as_int(wnt));
}

// ---------------------------------------------------------------------------
// Pull kernels: wave per bucket; HALF-WAVE per edge (bf16 row = 256B = 32
// lanes x ushort4). Main loop: 4 edges/iter (2 per half). Lane (half,hl)
// accumulates features hl*4..hl*4+3; cross-half shfl_xor(32) reduce at end.
__global__ void pull1_kernel(const int* __restrict__ start, const int2* __restrict__ edges,
                             const float* __restrict__ dinv,
                             const u16* __restrict__ xb_s, const u16* __restrict__ xb_t,
                             const float* __restrict__ x_s, const float* __restrict__ x_t,
                             u16* __restrict__ ab_s, u16* __restrict__ ab_t, int N) {
    int wid0 = (int)(((long long)blockIdx.x * blockDim.x + threadIdx.x) >> 6);
    int wid = __builtin_amdgcn_readfirstlane(wid0);
    int lane = threadIdx.x & 63;
    int half = lane >> 5, hl = lane & 31;
    if (wid >= 2 * N) return;
    const u16* xb; const float* x; u16* ab; int i, o;
    if (wid < N) { i = wid;     o = N; xb = xb_s; x = x_s; ab = ab_s; }
    else         { i = wid - N; o = 0; xb = xb_t; x = x_t; ab = ab_t; }
    int s0 = start[wid], s1 = start[wid + 1];
    float a0 = 0.f, a1 = 0.f, a2 = 0.f, a3 = 0.f;
    int k = s0;
    for (; k + 4 <= s1; k += 4) {
        int2 p0 = edges[k + 2 * half];
        int2 p1 = edges[k + 2 * half + 1];
        ushort4 v0 = *(const ushort4*)(xb + (size_t)p0.x * D + hl * 4);
        ushort4 v1 = *(const ushort4*)(xb + (size_t)p1.x * D + hl * 4);
        float w0v = __int_as_float(p0.y), w1v = __int_as_float(p1.y);
        a0 += w0v * bf2f(v0.x) + w1v * bf2f(v1.x);
        a1 += w0v * bf2f(v0.y) + w1v * bf2f(v1.y);
        a2 += w0v * bf2f(v0.z) + w1v * bf2f(v1.z);
        a3 += w0v * bf2f(v0.w) + w1v * bf2f(v1.w);
    }
    for (; k < s1; ++k) {
        if (half == 0) {
            int2 p = edges[k];
            ushort4 v = *(const ushort4*)(xb + (size_t)p.x * D + hl * 4);
            float wv = __int_as_float(p.y);
            a0 += wv * bf2f(v.x); a1 += wv * bf2f(v.y);
            a2 += wv * bf2f(v.z); a3 += wv * bf2f(v.w);
        }
    }
    a0 += __shfl_xor(a0, 32); a1 += __shfl_xor(a1, 32);
    a2 += __shfl_xor(a2, 32); a3 += __shfl_xor(a3, 32);
    if (half == 0) {
        float sw = FILLV * dinv[o + i];
        float4 xv = *(const float4*)(x + (size_t)i * D + hl * 4);
        a0 += sw * xv.x; a1 += sw * xv.y; a2 += sw * xv.z; a3 += sw * xv.w;
        ushort4 ov;
        ov.x = f2bf(a0); ov.y = f2bf(a1); ov.z = f2bf(a2); ov.w = f2bf(a3);
        *(ushort4*)(ab + (size_t)i * D + hl * 4) = ov;
    }
}

// Hop-2 pull + fused epilogue: out_half = w0*x + w1*a + w2*(conv(a)).
__global__ void pull2_kernel(const int* __restrict__ start, const int2* __restrict__ edges,
                             const float* __restrict__ dinv,
                             const u16* __restrict__ ab_s, const u16* __restrict__ ab_t,
                             const float* __restrict__ x_s, const float* __restrict__ x_t,
                             float* __restrict__ out,
                             const float* __restrict__ w_s, const float* __restrict__ w_t, int N) {
    int wid0 = (int)(((long long)blockIdx.x * blockDim.x + threadIdx.x) >> 6);
    int wid = __builtin_amdgcn_readfirstlane(wid0);
    int lane = threadIdx.x & 63;
    int half = lane >> 5, hl = lane & 31;
    if (wid >= 2 * N) return;
    const u16* ab; const float* x; const float* wv3; int i, o, hoff;
    if (wid < N) { i = wid;     o = N; ab = ab_s; x = x_s; wv3 = w_s; hoff = 0; }
    else         { i = wid - N; o = 0; ab = ab_t; x = x_t; wv3 = w_t; hoff = D; }
    int s0 = start[wid], s1 = start[wid + 1];
    float a0 = 0.f, a1 = 0.f, a2 = 0.f, a3 = 0.f;
    int k = s0;
    for (; k + 4 <= s1; k += 4) {
        int2 p0 = edges[k + 2 * half];
        int2 p1 = edges[k + 2 * half + 1];
        ushort4 v0 = *(const ushort4*)(ab + (size_t)p0.x * D + hl * 4);
        ushort4 v1 = *(const ushort4*)(ab + (size_t)p1.x * D + hl * 4);
        float w0v = __int_as_float(p0.y), w1v = __int_as_float(p1.y);
        a0 += w0v * bf2f(v0.x) + w1v * bf2f(v1.x);
        a1 += w0v * bf2f(v0.y) + w1v * bf2f(v1.y);
        a2 += w0v * bf2f(v0.z) + w1v * bf2f(v1.z);
        a3 += w0v * bf2f(v0.w) + w1v * bf2f(v1.w);
    }
    for (; k < s1; ++k) {
        if (half == 0) {
            int2 p = edges[k];
            ushort4 v = *(const ushort4*)(ab + (size_t)p.x * D + hl * 4);
            float wv = __int_as_float(p.y);
            a0 += wv * bf2f(v.x); a1 += wv * bf2f(v.y);
            a2 += wv * bf2f(v.z); a3 += wv * bf2f(v.w);
        }
    }
    a0 += __shfl_xor(a0, 32); a1 += __shfl_xor(a1, 32);
    a2 += __shfl_xor(a2, 32); a3 += __shfl_xor(a3, 32);
    if (half == 0) {
        float sw = FILLV * dinv[o + i];
        ushort4 av = *(const ushort4*)(ab + (size_t)i * D + hl * 4);
        float b0 = bf2f(av.x), b1 = bf2f(av.y), b2 = bf2f(av.z), b3 = bf2f(av.w);
        a0 += sw * b0; a1 += sw * b1; a2 += sw * b2; a3 += sw * b3;
        float w0 = wv3[0], w1 = wv3[1], w2 = wv3[2];
        float4 xv = *(const float4*)(x + (size_t)i * D + hl * 4);
        float4 ov;
        ov.x = w0 * xv.x + w1 * b0 + w2 * a0;
        ov.y = w0 * xv.y + w1 * b1 + w2 * a1;
        ov.z = w0 * xv.z + w1 * b2 + w2 * a2;
        ov.w = w0 * xv.w + w1 * b3 + w2 * a3;
        *(float4*)(out + (size_t)i * 2 * D + hoff + hl * 4) = ov;
    }
}

// ---------------------------------------------------------------------------
extern "C" void kernel_launch(void* const* d_in, const int* in_sizes, int n_in,
                              void* d_out, int out_size, void* d_ws, size_t ws_size,
                              hipStream_t stream) {
    const float* x_s = (const float*)d_in[0];
    const float* x_t = (const float*)d_in[1];
    const int*   ei  = (const int*)d_in[2];
    const float* ew  = (const float*)d_in[3];
    const float* w_s = (const float*)d_in[4];
    const float* w_t = (const float*)d_in[5];
    const int N = in_sizes[0] / D;
    const int E = in_sizes[3];
    const int* row = ei;
    const int* col = ei + E;

    const int total = 2 * N;
    const int nTiles = (total + 255) / 256;        // <= 512

    // Workspace: [dinv 2N][start 2N+2][tsum 512][toff 512][edges 2E int2]
    // [xb_s ND u16][xb_t ND u16][ab_s ND u16][ab_t ND u16]
    // Padded cntp (2N*PAD ints) aliases ab_s: dead before pull1 writes ab_s.
    float* f      = (float*)d_ws;
    float* dinv   = f;                              // 2N
    int*   start  = (int*)(f + (size_t)total);      // 2N+2
    int*   tsum   = start + (total + 2);
    int*   toff   = tsum + 512;
    int2*  edges  = (int2*)(toff + 512);            // 2E
    u16*   xb_s   = (u16*)(edges + 2 * (size_t)E);
    u16*   xb_t   = xb_s + (size_t)N * D;
    u16*   ab_s   = xb_t + (size_t)N * D;
    u16*   ab_t   = ab_s + (size_t)N * D;
    int*   cntp   = (int*)ab_s;                     // alias, dead before pull1
    float* out    = (float*)d_out;

    hipMemsetAsync(cntp, 0, (size_t)total * PAD * sizeof(int), stream);

    long long nd = (long long)N * D;
    int blkC  = (int)((nd / 2 + 255) / 256);
    int blkE  = (E + 255) / 256;
    int blk2N = (total + 255) / 256;
    tobf_kernel<<<blkC, 256, 0, stream>>>(x_s, x_t, xb_s, xb_t, nd);
    cnt_deg_kernel<<<blkE, 256, 0, stream>>>(row, col, ew, cntp, E, N);
    invert_kernel<<<blk2N, 256, 0, stream>>>(cntp, dinv, total);
    scanA_kernel<<<nTiles, 256, 0, stream>>>(cntp, tsum, total);
    scanB_kernel<<<1, 512, 0, stream>>>(tsum, toff, nTiles);
    scanC_kernel<<<nTiles, 256, 0, stream>>>(cntp, toff, start, total, 2 * E);
    fill_kernel<<<blkE, 256, 0, stream>>>(row, col, ew, dinv, cntp, edges, E, N);

    long long pull_threads = (long long)total * 64;
    int blkP = (int)((pull_threads + 255) / 256);
    pull1_kernel<<<blkP, 256, 0, stream>>>(start, edges, dinv, xb_s, xb_t,
                                           x_s, x_t, ab_s, ab_t, N);
    pull2_kernel<<<blkP, 256, 0, stream>>>(start, edges, dinv, ab_s, ab_t,
                                           x_s, x_t, out, w_s, w_t, N);
}

// Round 8
// 458.149 us; speedup vs baseline: 1.3648x; 1.1477x over previous
//
#include <hip/hip_runtime.h>

#define D 128
#define FILLV 0.5f
#define PAD 16   // counters strided to 64B lines

typedef unsigned short u16;
typedef unsigned long long u64;

__device__ __forceinline__ u16 f2bf(float f) {          // RNE fp32 -> bf16
    unsigned u = __float_as_uint(f);
    u += 0x7FFF + ((u >> 16) & 1);
    return (u16)(u >> 16);
}
__device__ __forceinline__ float bf2f(u16 h) {
    return __uint_as_float(((unsigned)h) << 16);
}

// ---------------------------------------------------------------------------
// Convert both feature matrices to bf16 staging copies (RNE).
__global__ void tobf_kernel(const float* __restrict__ x_s, const float* __restrict__ x_t,
                            u16* __restrict__ xb_s, u16* __restrict__ xb_t, long long nd) {
    long long t = (long long)blockIdx.x * blockDim.x + threadIdx.x;
    long long q = nd / 4;
    const float* x; u16* xb; long long i;
    if (t < q) { x = x_s; xb = xb_s; i = t * 4; }
    else if (t < 2 * q) { x = x_t; xb = xb_t; i = (t - q) * 4; }
    else return;
    float4 v = *(const float4*)(x + i);
    ushort4 o;
    o.x = f2bf(v.x); o.y = f2bf(v.y); o.z = f2bf(v.z); o.w = f2bf(v.w);
    *(ushort4*)(xb + i) = o;
}

// Pass 1: ONE packed 64-bit atomic per edge-direction:
//   high word += 1 (count), low word += w * 2^24 (fixed-point degree).
// Max degree ~60 << 256, so the fixed sum (< 2^24*256 = 2^32) never carries
// into the count word. Line j<N keyed by col, line N+r keyed by row.
__global__ void cnt_deg_kernel(const int* __restrict__ row, const int* __restrict__ col,
                               const float* __restrict__ w,
                               u64* __restrict__ cntp64, int E, int N) {
    int e = blockIdx.x * blockDim.x + threadIdx.x;
    if (e >= E) return;
    int r = row[e], c = col[e];
    unsigned fx = (unsigned)(w[e] * 16777216.0f);       // w * 2^24
    u64 add = (1ull << 32) | fx;
    atomicAdd(&cntp64[(size_t)c * (PAD / 2)], add);
    atomicAdd(&cntp64[(size_t)(N + r) * (PAD / 2)], add);
}

// Unpack: dinv[i] = 1/(deg+FILL); re-store plain count for the scan phases.
__global__ void invert_kernel(int* __restrict__ cntp, float* __restrict__ dinv, int total) {
    int i = blockIdx.x * blockDim.x + threadIdx.x;
    if (i >= total) return;
    u64 v = *(const u64*)&cntp[(size_t)i * PAD];
    float deg = (float)(unsigned)(v & 0xffffffffu) * (1.0f / 16777216.0f);
    dinv[i] = 1.0f / (deg + FILLV);
    cntp[(size_t)i * PAD] = (int)(v >> 32);
}

// --------------------------- 3-phase parallel scan --------------------------
__global__ void scanA_kernel(const int* __restrict__ cntp, int* __restrict__ tsum, int total) {
    __shared__ int sh[256];
    int gid = blockIdx.x * 256 + threadIdx.x;
    sh[threadIdx.x] = (gid < total) ? cntp[(size_t)gid * PAD] : 0;
    __syncthreads();
    for (int off = 128; off > 0; off >>= 1) {
        if (threadIdx.x < off) sh[threadIdx.x] += sh[threadIdx.x + off];
        __syncthreads();
    }
    if (threadIdx.x == 0) tsum[blockIdx.x] = sh[0];
}

__global__ void scanB_kernel(const int* __restrict__ tsum, int* __restrict__ toff, int nt) {
    __shared__ int sh[512];
    int t = threadIdx.x;
    int v = (t < nt) ? tsum[t] : 0;
    sh[t] = v;
    __syncthreads();
    for (int off = 1; off < 512; off <<= 1) {
        int u = 0;
        if (t >= off) u = sh[t - off];
        __syncthreads();
        sh[t] += u;
        __syncthreads();
    }
    if (t < nt) toff[t] = sh[t] - v;
}

__global__ void scanC_kernel(int* __restrict__ cntp, const int* __restrict__ toff,
                             int* __restrict__ start, int total, int grand_total) {
    __shared__ int sh[256];
    int gid = blockIdx.x * 256 + threadIdx.x;
    int v = (gid < total) ? cntp[(size_t)gid * PAD] : 0;
    sh[threadIdx.x] = v;
    __syncthreads();
    for (int off = 1; off < 256; off <<= 1) {
        int u = 0;
        if (threadIdx.x >= off) u = sh[threadIdx.x - off];
        __syncthreads();
        sh[threadIdx.x] += u;
        __syncthreads();
    }
    int run = toff[blockIdx.x] + sh[threadIdx.x] - v;   // exclusive
    if (gid < total) {
        start[gid] = run;
        cntp[(size_t)gid * PAD] = run;   // becomes fill cursor
    }
    if (gid == 0) start[total] = grand_total;
}

// Pass 2: scatter edges with dinv pre-folded: payload = (src, w*dinv[src-key]).
__global__ void fill_kernel(const int* __restrict__ row, const int* __restrict__ col,
                            const float* __restrict__ w, const float* __restrict__ dinv,
                            int* __restrict__ cntp, int2* __restrict__ edges, int E, int N) {
    int e = blockIdx.x * blockDim.x + threadIdx.x;
    if (e >= E) return;
    int r = row[e], c = col[e];
    float we = w[e];
    float wns = we * dinv[N + r];   // s-side: normalize by deg_s (row key)
    float wnt = we * dinv[c];       // t-side: normalize by deg_t (col key)
    int ps = atomicAdd(&cntp[(size_t)c * PAD], 1);
    edges[ps] = make_int2(r, __float_as_int(wns));
    int pt = atomicAdd(&cntp[((size_t)N + r) * PAD], 1);
    edges[pt] = make_int2(c, __float_as_int(wnt));
}

// ---------------------------------------------------------------------------
// Pull kernels: wave per bucket; HALF-WAVE per edge (bf16 row = 256B = 32
// lanes x ushort4). Main loop: 8 edges/iter (4 per half, 4 gathers in flight);
// mid step 4; tail by half 0. Payload loads are wave-uniform -> s_load.
__global__ void pull1_kernel(const int* __restrict__ start, const int2* __restrict__ edges,
                             const float* __restrict__ dinv,
                             const u16* __restrict__ xb_s, const u16* __restrict__ xb_t,
                             const float* __restrict__ x_s, const float* __restrict__ x_t,
                             u16* __restrict__ ab_s, u16* __restrict__ ab_t, int N) {
    int wid0 = (int)(((long long)blockIdx.x * blockDim.x + threadIdx.x) >> 6);
    int wid = __builtin_amdgcn_readfirstlane(wid0);
    int lane = threadIdx.x & 63;
    int half = lane >> 5, hl = lane & 31;
    if (wid >= 2 * N) return;
    const u16* xb; const float* x; u16* ab; int i, o;
    if (wid < N) { i = wid;     o = N; xb = xb_s; x = x_s; ab = ab_s; }
    else         { i = wid - N; o = 0; xb = xb_t; x = x_t; ab = ab_t; }
    int s0 = start[wid], s1 = start[wid + 1];
    float a0 = 0.f, a1 = 0.f, a2 = 0.f, a3 = 0.f;
    int k = s0;
    for (; k + 8 <= s1; k += 8) {
        int b = k + 4 * half;
        int2 p0 = edges[b], p1 = edges[b + 1], p2 = edges[b + 2], p3 = edges[b + 3];
        ushort4 v0 = *(const ushort4*)(xb + (size_t)p0.x * D + hl * 4);
        ushort4 v1 = *(const ushort4*)(xb + (size_t)p1.x * D + hl * 4);
        ushort4 v2 = *(const ushort4*)(xb + (size_t)p2.x * D + hl * 4);
        ushort4 v3 = *(const ushort4*)(xb + (size_t)p3.x * D + hl * 4);
        float w0v = __int_as_float(p0.y), w1v = __int_as_float(p1.y);
        float w2v = __int_as_float(p2.y), w3v = __int_as_float(p3.y);
        a0 += w0v * bf2f(v0.x) + w1v * bf2f(v1.x) + w2v * bf2f(v2.x) + w3v * bf2f(v3.x);
        a1 += w0v * bf2f(v0.y) + w1v * bf2f(v1.y) + w2v * bf2f(v2.y) + w3v * bf2f(v3.y);
        a2 += w0v * bf2f(v0.z) + w1v * bf2f(v1.z) + w2v * bf2f(v2.z) + w3v * bf2f(v3.z);
        a3 += w0v * bf2f(v0.w) + w1v * bf2f(v1.w) + w2v * bf2f(v2.w) + w3v * bf2f(v3.w);
    }
    if (k + 4 <= s1) {
        int b = k + 2 * half;
        int2 p0 = edges[b], p1 = edges[b + 1];
        ushort4 v0 = *(const ushort4*)(xb + (size_t)p0.x * D + hl * 4);
        ushort4 v1 = *(const ushort4*)(xb + (size_t)p1.x * D + hl * 4);
        float w0v = __int_as_float(p0.y), w1v = __int_as_float(p1.y);
        a0 += w0v * bf2f(v0.x) + w1v * bf2f(v1.x);
        a1 += w0v * bf2f(v0.y) + w1v * bf2f(v1.y);
        a2 += w0v * bf2f(v0.z) + w1v * bf2f(v1.z);
        a3 += w0v * bf2f(v0.w) + w1v * bf2f(v1.w);
        k += 4;
    }
    for (; k < s1; ++k) {
        if (half == 0) {
            int2 p = edges[k];
            ushort4 v = *(const ushort4*)(xb + (size_t)p.x * D + hl * 4);
            float wv = __int_as_float(p.y);
            a0 += wv * bf2f(v.x); a1 += wv * bf2f(v.y);
            a2 += wv * bf2f(v.z); a3 += wv * bf2f(v.w);
        }
    }
    a0 += __shfl_xor(a0, 32); a1 += __shfl_xor(a1, 32);
    a2 += __shfl_xor(a2, 32); a3 += __shfl_xor(a3, 32);
    if (half == 0) {
        float sw = FILLV * dinv[o + i];
        float4 xv = *(const float4*)(x + (size_t)i * D + hl * 4);
        a0 += sw * xv.x; a1 += sw * xv.y; a2 += sw * xv.z; a3 += sw * xv.w;
        ushort4 ov;
        ov.x = f2bf(a0); ov.y = f2bf(a1); ov.z = f2bf(a2); ov.w = f2bf(a3);
        *(ushort4*)(ab + (size_t)i * D + hl * 4) = ov;
    }
}

// Hop-2 pull + fused epilogue: out_half = w0*x + w1*a + w2*(conv(a)).
__global__ void pull2_kernel(const int* __restrict__ start, const int2* __restrict__ edges,
                             const float* __restrict__ dinv,
                             const u16* __restrict__ ab_s, const u16* __restrict__ ab_t,
                             const float* __restrict__ x_s, const float* __restrict__ x_t,
                             float* __restrict__ out,
                             const float* __restrict__ w_s, const float* __restrict__ w_t, int N) {
    int wid0 = (int)(((long long)blockIdx.x * blockDim.x + threadIdx.x) >> 6);
    int wid = __builtin_amdgcn_readfirstlane(wid0);
    int lane = threadIdx.x & 63;
    int half = lane >> 5, hl = lane & 31;
    if (wid >= 2 * N) return;
    const u16* ab; const float* x; const float* wv3; int i, o, hoff;
    if (wid < N) { i = wid;     o = N; ab = ab_s; x = x_s; wv3 = w_s; hoff = 0; }
    else         { i = wid - N; o = 0; ab = ab_t; x = x_t; wv3 = w_t; hoff = D; }
    int s0 = start[wid], s1 = start[wid + 1];
    float a0 = 0.f, a1 = 0.f, a2 = 0.f, a3 = 0.f;
    int k = s0;
    for (; k + 8 <= s1; k += 8) {
        int b = k + 4 * half;
        int2 p0 = edges[b], p1 = edges[b + 1], p2 = edges[b + 2], p3 = edges[b + 3];
        ushort4 v0 = *(const ushort4*)(ab + (size_t)p0.x * D + hl * 4);
        ushort4 v1 = *(const ushort4*)(ab + (size_t)p1.x * D + hl * 4);
        ushort4 v2 = *(const ushort4*)(ab + (size_t)p2.x * D + hl * 4);
        ushort4 v3 = *(const ushort4*)(ab + (size_t)p3.x * D + hl * 4);
        float w0v = __int_as_float(p0.y), w1v = __int_as_float(p1.y);
        float w2v = __int_as_float(p2.y), w3v = __int_as_float(p3.y);
        a0 += w0v * bf2f(v0.x) + w1v * bf2f(v1.x) + w2v * bf2f(v2.x) + w3v * bf2f(v3.x);
        a1 += w0v * bf2f(v0.y) + w1v * bf2f(v1.y) + w2v * bf2f(v2.y) + w3v * bf2f(v3.y);
        a2 += w0v * bf2f(v0.z) + w1v * bf2f(v1.z) + w2v * bf2f(v2.z) + w3v * bf2f(v3.z);
        a3 += w0v * bf2f(v0.w) + w1v * bf2f(v1.w) + w2v * bf2f(v2.w) + w3v * bf2f(v3.w);
    }
    if (k + 4 <= s1) {
        int b = k + 2 * half;
        int2 p0 = edges[b], p1 = edges[b + 1];
        ushort4 v0 = *(const ushort4*)(ab + (size_t)p0.x * D + hl * 4);
        ushort4 v1 = *(const ushort4*)(ab + (size_t)p1.x * D + hl * 4);
        float w0v = __int_as_float(p0.y), w1v = __int_as_float(p1.y);
        a0 += w0v * bf2f(v0.x) + w1v * bf2f(v1.x);
        a1 += w0v * bf2f(v0.y) + w1v * bf2f(v1.y);
        a2 += w0v * bf2f(v0.z) + w1v * bf2f(v1.z);
        a3 += w0v * bf2f(v0.w) + w1v * bf2f(v1.w);
        k += 4;
    }
    for (; k < s1; ++k) {
        if (half == 0) {
            int2 p = edges[k];
            ushort4 v = *(const ushort4*)(ab + (size_t)p.x * D + hl * 4);
            float wv = __int_as_float(p.y);
            a0 += wv * bf2f(v.x); a1 += wv * bf2f(v.y);
            a2 += wv * bf2f(v.z); a3 += wv * bf2f(v.w);
        }
    }
    a0 += __shfl_xor(a0, 32); a1 += __shfl_xor(a1, 32);
    a2 += __shfl_xor(a2, 32); a3 += __shfl_xor(a3, 32);
    if (half == 0) {
        float sw = FILLV * dinv[o + i];
        ushort4 av = *(const ushort4*)(ab + (size_t)i * D + hl * 4);
        float b0 = bf2f(av.x), b1 = bf2f(av.y), b2 = bf2f(av.z), b3 = bf2f(av.w);
        a0 += sw * b0; a1 += sw * b1; a2 += sw * b2; a3 += sw * b3;
        float w0 = wv3[0], w1 = wv3[1], w2 = wv3[2];
        float4 xv = *(const float4*)(x + (size_t)i * D + hl * 4);
        float4 ov;
        ov.x = w0 * xv.x + w1 * b0 + w2 * a0;
        ov.y = w0 * xv.y + w1 * b1 + w2 * a1;
        ov.z = w0 * xv.z + w1 * b2 + w2 * a2;
        ov.w = w0 * xv.w + w1 * b3 + w2 * a3;
        *(float4*)(out + (size_t)i * 2 * D + hoff + hl * 4) = ov;
    }
}

// ---------------------------------------------------------------------------
extern "C" void kernel_launch(void* const* d_in, const int* in_sizes, int n_in,
                              void* d_out, int out_size, void* d_ws, size_t ws_size,
                              hipStream_t stream) {
    const float* x_s = (const float*)d_in[0];
    const float* x_t = (const float*)d_in[1];
    const int*   ei  = (const int*)d_in[2];
    const float* ew  = (const float*)d_in[3];
    const float* w_s = (const float*)d_in[4];
    const float* w_t = (const float*)d_in[5];
    const int N = in_sizes[0] / D;
    const int E = in_sizes[3];
    const int* row = ei;
    const int* col = ei + E;

    const int total = 2 * N;
    const int nTiles = (total + 255) / 256;        // <= 512

    // Workspace: [dinv 2N][start 2N+2][tsum 512][toff 512][edges 2E int2]
    // [xb_s ND u16][xb_t ND u16][ab_s ND u16][ab_t ND u16]
    // Padded cntp (2N*PAD ints) aliases ab_s (8B-aligned): dead before pull1.
    float* f      = (float*)d_ws;
    float* dinv   = f;                              // 2N
    int*   start  = (int*)(f + (size_t)total);      // 2N+2
    int*   tsum   = start + (total + 2);
    int*   toff   = tsum + 512;
    int2*  edges  = (int2*)(toff + 512);            // 2E
    u16*   xb_s   = (u16*)(edges + 2 * (size_t)E);
    u16*   xb_t   = xb_s + (size_t)N * D;
    u16*   ab_s   = xb_t + (size_t)N * D;
    u16*   ab_t   = ab_s + (size_t)N * D;
    int*   cntp   = (int*)ab_s;                     // alias, dead before pull1
    float* out    = (float*)d_out;

    hipMemsetAsync(cntp, 0, (size_t)total * PAD * sizeof(int), stream);

    long long nd = (long long)N * D;
    int blkC  = (int)((nd / 2 + 255) / 256);
    int blkE  = (E + 255) / 256;
    int blk2N = (total + 255) / 256;
    tobf_kernel<<<blkC, 256, 0, stream>>>(x_s, x_t, xb_s, xb_t, nd);
    cnt_deg_kernel<<<blkE, 256, 0, stream>>>(row, col, ew, (u64*)cntp, E, N);
    invert_kernel<<<blk2N, 256, 0, stream>>>(cntp, dinv, total);
    scanA_kernel<<<nTiles, 256, 0, stream>>>(cntp, tsum, total);
    scanB_kernel<<<1, 512, 0, stream>>>(tsum, toff, nTiles);
    scanC_kernel<<<nTiles, 256, 0, stream>>>(cntp, toff, start, total, 2 * E);
    fill_kernel<<<blkE, 256, 0, stream>>>(row, col, ew, dinv, cntp, edges, E, N);

    long long pull_threads = (long long)total * 64;
    int blkP = (int)((pull_threads + 255) / 256);
    pull1_kernel<<<blkP, 256, 0, stream>>>(start, edges, dinv, xb_s, xb_t,
                                           x_s, x_t, ab_s, ab_t, N);
    pull2_kernel<<<blkP, 256, 0, stream>>>(start, edges, dinv, ab_s, ab_t,
                                           x_s, x_t, out, w_s, w_t, N);
}